// Round 8
// baseline (173.462 us; speedup 1.0000x reference)
//
#include <hip/hip_runtime.h>
#include <hip/hip_bf16.h>
#include <math.h>

#define NTOK 65536
#define DMODEL 256
#define NEXP 8
#define CAP 65536
#define MAXTILES 1040
#define CSTRIDE 64   // counter spacing in ints (256 B) - one L2 line per expert

typedef __bf16 bf16_t;
typedef __bf16 bf16x8 __attribute__((ext_vector_type(8)));
typedef float f32x4 __attribute__((ext_vector_type(4)));

// async global->LDS, 16B per lane. Global addr may be per-lane (gather);
// LDS dest = wave-uniform base + lane*16.
__device__ inline void async16(const void* g, void* l) {
  __builtin_amdgcn_global_load_lds(
      (const __attribute__((address_space(1))) unsigned int*)g,
      (__attribute__((address_space(3))) unsigned int*)l, 16, 0, 0);
}

// Gate v9: 512 blocks x 128 tokens (2 passes of 64), ping-pong staging.
//  - two 32KB stage buffers; stage(u+1) is issued BEFORE compute(u), so the
//    barrier that drains it sits at its consumption point (v8 issued the
//    second stage between two barriers = fully exposed latency).
//  - ONE atomicAdd per expert per block covering both passes: same-line
//    returning-atomic chain 1024 -> 512 deep (~13.4ns each, prior session).
//  - per-half dot chains, cast pass, reduce, softmax: v8 verbatim.
//  - weight pack fused (4 fragments/block now; layout identical to round 7).
__global__ __launch_bounds__(256) void gate_pack_kernel(
    const float* __restrict__ x, const float* __restrict__ wg,
    const float* __restrict__ W1, const float* __restrict__ W2,
    bf16_t* __restrict__ xb, float* __restrict__ gateval,
    int* __restrict__ counts, int* __restrict__ idxbuf,
    bf16_t* __restrict__ w1p, bf16_t* __restrict__ w2p) {
  __shared__ __align__(16) float xs[2][64 * 128];  // 64 KB ping-pong
  __shared__ double part[3][64][9];                // 13.5 KB
  const int th = threadIdx.x;
  const int lane = th & 63;
  const int wv = th >> 6;                          // 0..3
  const int tokbase = blockIdx.x * 128;
  const int xm = lane & 31;

  // stage unit u: pass = u>>1, half = u&1, rows tokbase + (u>>1)*64 + r
  auto stage = [&](int u) {
#pragma unroll
    for (int i = 0; i < 8; ++i) {
      int p = i * 256 + th;
      int r = p >> 5, c = (p & 31) ^ (r & 31);
      async16(x + (size_t)(tokbase + (u >> 1) * 64 + r) * 256 + (u & 1) * 128 + c * 4,
              &xs[u & 1][(i * 256 + wv * 64) * 4]);
    }
  };

  stage(0);
  // ---- pack 4 weight fragments (overlaps stage-0 latency). Layout
  // identical to round-7 (validated): frag f -> mat, e, kf, nt.
#pragma unroll
  for (int jj = 0; jj < 4; ++jj) {
    int f = blockIdx.x * 4 + jj;
    int mat = f >> 10, e = (f >> 7) & 7, kf = (f >> 4) & 7, nt = f & 15;
    const float* src = (mat == 0 ? W1 : W2) + (size_t)e * 65536;
    bf16_t* dst = (mat == 0 ? w1p : w2p) + (((size_t)e * 8 + kf) * 16 + nt) * 512;
#pragma unroll
    for (int rep = 0; rep < 2; ++rep) {
      int kl = rep * 16 + (th >> 4), nl = th & 15;
      float v = src[(size_t)(kf * 32 + kl) * 256 + nt * 16 + nl];
      int lanep = nl + 16 * (kl >> 3), j = kl & 7;
      dst[lanep * 8 + j] = (bf16_t)v;
    }
  }
  __syncthreads();   // unit 0 landed

  int bi0 = 0, bi1 = 0;
  double acc[8] = {0, 0, 0, 0, 0, 0, 0, 0};
#pragma unroll
  for (int u = 0; u < 4; ++u) {
    if (u < 3) stage(u + 1);             // prefetch next unit into other buf
    const float* xh = xs[u & 1];
    const int h = u & 1, ps = u >> 1;
    // cast pass: 1024 bf16 16B-slots -> contiguous xb stores
#pragma unroll
    for (int i = 0; i < 4; ++i) {
      int p = i * 256 + th;
      int r = p >> 4, cb = p & 15, mk = r & 31;
      f32x4 a = *(const f32x4*)&xh[r * 128 + (((2 * cb) ^ mk) * 4)];
      f32x4 b = *(const f32x4*)&xh[r * 128 + (((2 * cb + 1) ^ mk) * 4)];
      bf16x8 bv;
      bv[0] = (bf16_t)a[0]; bv[1] = (bf16_t)a[1];
      bv[2] = (bf16_t)a[2]; bv[3] = (bf16_t)a[3];
      bv[4] = (bf16_t)b[0]; bv[5] = (bf16_t)b[1];
      bv[6] = (bf16_t)b[2]; bv[7] = (bf16_t)b[3];
      *(bf16x8*)(xb + (size_t)(tokbase + ps * 64 + r) * 256 + h * 128 + cb * 8) = bv;
    }
    // dot: wave wv covers dims h*128 + wv*32..+32 (4 chains of 8)
#pragma unroll
    for (int g = 0; g < 4; ++g) {
      int c0 = wv * 8 + 2 * g;
      f32x4 a = *(const f32x4*)&xh[lane * 128 + ((c0 ^ xm) * 4)];
      f32x4 b = *(const f32x4*)&xh[lane * 128 + (((c0 + 1) ^ xm) * 4)];
      float xv[8] = {a[0], a[1], a[2], a[3], b[0], b[1], b[2], b[3]};
#pragma unroll
      for (int e = 0; e < 8; ++e) {
        const float* wge = wg + e * 256 + h * 128 + wv * 32 + g * 8;  // uniform
        float s = 0.f;
#pragma unroll
        for (int j2 = 0; j2 < 8; ++j2) s = fmaf(xv[j2], wge[j2], s);
        acc[e] += (double)s;
      }
    }
    if (u & 1) {   // end of pass ps: reduce + per-pass tail
      if (wv > 0) {
#pragma unroll
        for (int e = 0; e < 8; ++e) part[wv - 1][lane][e] = acc[e];
      }
      __syncthreads();
      if (wv == 0) {
        double a2[8];
#pragma unroll
        for (int e = 0; e < 8; ++e) a2[e] = acc[e];
#pragma unroll
        for (int s2 = 0; s2 < 3; ++s2)
#pragma unroll
          for (int e = 0; e < 8; ++e) a2[e] += part[s2][lane][e];
        double m = a2[0]; int bi = 0;
#pragma unroll
        for (int e = 1; e < 8; ++e) if (a2[e] > m) { m = a2[e]; bi = e; }
        float denom = 0.f;
#pragma unroll
        for (int e = 0; e < 8; ++e) denom += __expf((float)(a2[e] - m));
        gateval[tokbase + ps * 64 + lane] = 1.0f / denom;
        if (ps == 0) bi0 = bi; else bi1 = bi;
      }
#pragma unroll
      for (int e = 0; e < 8; ++e) acc[e] = 0.0;
      __syncthreads();   // part safe to rewrite; next buf drained
    } else {
      __syncthreads();   // next unit's buf drained
    }
  }

  // ---- combined tail: one atomic per expert for both passes ----
  if (wv == 0) {
    const unsigned long long below = (1ull << lane) - 1ull;
    int myc = 0;
#pragma unroll
    for (int e = 0; e < NEXP; ++e) {
      unsigned long long mk0 = __ballot(bi0 == e);
      unsigned long long mk1 = __ballot(bi1 == e);
      if (lane == e) myc = (int)__popcll(mk0) + (int)__popcll(mk1);
    }
    int mybase = 0;
    if (lane < NEXP) mybase = atomicAdd(&counts[lane * CSTRIDE], myc);
#pragma unroll
    for (int e = 0; e < NEXP; ++e) {
      unsigned long long mk0 = __ballot(bi0 == e);
      unsigned long long mk1 = __ballot(bi1 == e);
      int b0 = __shfl(mybase, e, 64);
      if (bi0 == e)
        idxbuf[e * CAP + b0 + (int)__popcll(mk0 & below)] = tokbase + lane;
      if (bi1 == e)
        idxbuf[e * CAP + b0 + (int)__popcll(mk0) + (int)__popcll(mk1 & below)] =
            tokbase + 64 + lane;
    }
  }
}

// Fused MoE GEMM v6 = round-7 body (coalesced packed-B, validated) with a
// vectorized epilogue: round-7 counters showed 93 MB at only 2.07 TB/s with
// all pipes <28% -- the 32 scalar 4B stores/thread (64B fragments over 4
// rows per instr) are the last bad access pattern. New epilogue bounces each
// wave's 64x32 f32 strip through its private 4KB of ts (dead after phase 2;
// word-rotated layout: writes 2-way, reads even) then stores 16B/lane
// dwordx4 = 128B contiguous per row; store instrs 32 -> 8 per thread.
// (acc+bias)*gate arithmetic unchanged -> bit-identical values.
__global__ __launch_bounds__(512, 4) void moe_gemm_kernel(
    const bf16_t* __restrict__ xb, const bf16_t* __restrict__ w1p,
    const bf16_t* __restrict__ w2p, const float* __restrict__ b1,
    const float* __restrict__ b2, const float* __restrict__ gateval,
    const int* __restrict__ counts, const int* __restrict__ idxbuf,
    float* __restrict__ out) {
  int ex = -1, tm = 0, a2 = 0, cnte = 0;
#pragma unroll
  for (int e2 = 0; e2 < 8; ++e2) {
    int c = counts[e2 * CSTRIDE];
    int n = (c + 63) >> 6;
    if ((int)blockIdx.x >= a2 && (int)blockIdx.x < a2 + n) {
      ex = e2; tm = (int)blockIdx.x - a2; cnte = c;
    }
    a2 += n;
  }
  if (ex < 0) return;
  const int ccnt = cnte;
  __shared__ __align__(16) bf16_t ts[64 * 256];   // x tile -> h tile -> f32 bounce
  __shared__ int sidx[64];
  __shared__ float sgv[64];
  const int th = threadIdx.x;
  const int lane = th & 63, wv = th >> 6;         // wv 0..7
  const int lr = lane & 15, lq = lane >> 4;
  if (th < 64) {
    int r = tm * 64 + th;
    int t = idxbuf[ex * CAP + (r < ccnt ? r : ccnt - 1)];
    sidx[th] = t;
    sgv[th] = gateval[t];
  }
  __syncthreads();
#pragma unroll
  for (int i = 0; i < 4; ++i) {
    int p = i * 512 + th;
    int r = p >> 5, s = (p & 31) ^ (r & 31);
    async16(xb + (size_t)sidx[r] * 256 + s * 8, &ts[(i * 512 + wv * 64) * 8]);
  }
  __syncthreads();

  // ---- Phase 1: h = relu(x @ W1 + b1), wave wv owns cols wv*32..+32 ----
  const bf16_t* w1e = w1p + (size_t)ex * 65536;
  {
    f32x4 acc[4][2] = {};
#pragma unroll
    for (int kk = 0; kk < 256; kk += 64) {
#pragma unroll
      for (int kb = 0; kb < 2; ++kb) {
        const int ks = (kk >> 3) + kb * 4 + lq;
        const int kf = (kk >> 5) + kb;
        bf16x8 af[4], bfr[2];
#pragma unroll
        for (int mi = 0; mi < 4; ++mi) {
          int r = mi * 16 + lr;
          af[mi] = *(const bf16x8*)&ts[(r * 32 + (ks ^ (r & 31))) * 8];
        }
#pragma unroll
        for (int ni = 0; ni < 2; ++ni)
          bfr[ni] = *(const bf16x8*)&w1e[((size_t)kf * 16 + wv * 2 + ni) * 512 + lane * 8];
#pragma unroll
        for (int mi = 0; mi < 4; ++mi)
#pragma unroll
          for (int ni = 0; ni < 2; ++ni)
            acc[mi][ni] = __builtin_amdgcn_mfma_f32_16x16x32_bf16(af[mi], bfr[ni], acc[mi][ni], 0, 0, 0);
      }
    }
    float b1v[2];
#pragma unroll
    for (int ni = 0; ni < 2; ++ni) b1v[ni] = b1[ex * 256 + wv * 32 + ni * 16 + lr];
    __syncthreads();   // all x-tile reads done before h overlay
#pragma unroll
    for (int mi = 0; mi < 4; ++mi)
#pragma unroll
      for (int ni = 0; ni < 2; ++ni)
#pragma unroll
        for (int rr = 0; rr < 4; ++rr) {
          int m = mi * 16 + lq * 4 + rr;
          int n = wv * 32 + ni * 16 + lr;
          float v = acc[mi][ni][rr] + b1v[ni];
          v = v > 0.f ? v : 0.f;
          ts[(m * 32 + ((n >> 3) ^ (m & 31))) * 8 + (n & 7)] = (bf16_t)v;
        }
  }
  __syncthreads();

  // ---- Phase 2: out = (h @ W2 + b2) * gate ----
  const bf16_t* w2e = w2p + (size_t)ex * 65536;
  {
    f32x4 acc[4][2] = {};
#pragma unroll
    for (int kk = 0; kk < 256; kk += 64) {
#pragma unroll
      for (int kb = 0; kb < 2; ++kb) {
        const int ks = (kk >> 3) + kb * 4 + lq;
        const int kf = (kk >> 5) + kb;
        bf16x8 af[4], bfr[2];
#pragma unroll
        for (int mi = 0; mi < 4; ++mi) {
          int r = mi * 16 + lr;
          af[mi] = *(const bf16x8*)&ts[(r * 32 + (ks ^ (r & 31))) * 8];
        }
#pragma unroll
        for (int ni = 0; ni < 2; ++ni)
          bfr[ni] = *(const bf16x8*)&w2e[((size_t)kf * 16 + wv * 2 + ni) * 512 + lane * 8];
#pragma unroll
        for (int mi = 0; mi < 4; ++mi)
#pragma unroll
          for (int ni = 0; ni < 2; ++ni)
            acc[mi][ni] = __builtin_amdgcn_mfma_f32_16x16x32_bf16(af[mi], bfr[ni], acc[mi][ni], 0, 0, 0);
      }
    }
    float b2v[2];
#pragma unroll
    for (int ni = 0; ni < 2; ++ni) b2v[ni] = b2[ex * 256 + wv * 32 + ni * 16 + lr];
    __syncthreads();   // phase-2 LDS reads done; ts becomes per-wave f32 bounce
    float* wb = (float*)&ts[0] + wv * 1024;   // private 4 KB per wave
#pragma unroll
    for (int bt = 0; bt < 2; ++bt) {          // rows bt*32..+32 of the tile
#pragma unroll
      for (int mi2 = 0; mi2 < 2; ++mi2) {
        const int mi = bt * 2 + mi2;
#pragma unroll
        for (int ni = 0; ni < 2; ++ni)
#pragma unroll
          for (int rr = 0; rr < 4; ++rr) {
            int lm = mi2 * 16 + lq * 4 + rr;     // local row 0..31
            int lc = ni * 16 + lr;               // local col 0..31
            int m = mi * 16 + lq * 4 + rr;
            float v = (acc[mi][ni][rr] + b2v[ni]) * sgv[m];
            int slot = ((lc >> 2) + (lm & 7)) & 7;   // word-rotated 16B slots
            wb[lm * 32 + slot * 4 + (lc & 3)] = v;
          }
      }
#pragma unroll
      for (int rd = 0; rd < 4; ++rd) {
        int lm = rd * 8 + (lane >> 3);
        int kk2 = lane & 7;
        int slot = (kk2 + (lm & 7)) & 7;
        f32x4 v = *(const f32x4*)&wb[lm * 32 + slot * 4];
        int m = bt * 32 + lm;
        int row = tm * 64 + m;
        if (row < ccnt)
          *(f32x4*)&out[(size_t)sidx[m] * 256 + wv * 32 + kk2 * 4] = v;
      }
    }
  }
}

extern "C" void kernel_launch(void* const* d_in, const int* in_sizes, int n_in,
                              void* d_out, int out_size, void* d_ws, size_t ws_size,
                              hipStream_t stream) {
  (void)in_sizes; (void)n_in; (void)out_size; (void)ws_size;
  const float* x  = (const float*)d_in[0];
  const float* wg = (const float*)d_in[1];
  const float* W1 = (const float*)d_in[2];
  const float* b1 = (const float*)d_in[3];
  const float* W2 = (const float*)d_in[4];
  const float* b2 = (const float*)d_in[5];
  float* out = (float*)d_out;

  char* ws = (char*)d_ws;
  size_t off = 0;
  auto alloc = [&](size_t bytes) {
    void* p = ws + off;
    off += (bytes + 255) & ~(size_t)255;
    return p;
  };
  bf16_t* xb     = (bf16_t*)alloc((size_t)NTOK * DMODEL * 2);   // 32 MB
  bf16_t* w1p    = (bf16_t*)alloc((size_t)NEXP * 256 * 256 * 2);
  bf16_t* w2p    = (bf16_t*)alloc((size_t)NEXP * 256 * 256 * 2);
  int*    idxbuf = (int*)alloc((size_t)NEXP * CAP * 4);         // 2 MB
  float*  gv     = (float*)alloc((size_t)NTOK * 4);
  int*    counts = (int*)alloc((size_t)NEXP * CSTRIDE * 4);     // 256B-spread

  hipMemsetAsync(counts, 0, (size_t)NEXP * CSTRIDE * 4, stream);
  hipLaunchKernelGGL(gate_pack_kernel, dim3(NTOK / 128), dim3(256), 0, stream,
                     x, wg, W1, W2, xb, gv, counts, idxbuf, w1p, w2p);
  hipLaunchKernelGGL(moe_gemm_kernel, dim3(MAXTILES), dim3(512), 0, stream,
                     xb, w1p, w2p, b1, b2, gv, counts, idxbuf, out);
}